// Round 18
// baseline (70.919 us; speedup 1.0000x reference)
//
#include <hip/hip_runtime.h>

// LSHAttention: reference returns ONLY sticker = argsort(buckets) [B,S] int32.
// B=4, S=4096, D=1024, NR=32, 64 buckets.
//
// ROUND 18: MAX BLOCK-LEVEL PARALLELISM. R7-R17 all plateaued at ~40us with
// every pipe <=25% busy and avg 5-11 waves/CU regardless of design; the
// never-tried config is many small INDEPENDENT blocks: 16-way K-split,
// stage-once + one barrier + straight-line compute, 24.6 KB LDS ->
// 6 blocks/CU = 24 waves/CU of mutually independent work.
//
// k1: grid 4096 = (b:4, chunk:64 -> 64 tok, ks:16 -> 64 k), 256 thr = 4 waves.
//   Wave w owns tokens [w*16, w*16+16). Prologue: DMA R-slice (8 KB, shared)
//   + Q (16 KB, 4 KB/wave), vmcnt(0), ONE barrier. Then pure compute:
//   2 passes of the R11-verified shape (rv[4][2] preload + qv-per-j), 512 FMA
//   + 32 ds_read_b128 per thread, acc 8tok x 8r (R11-measured 84 VGPR).
//   Swizzles verbatim from R11/R17 (verified): R slot v^((kh>>3)&7) via
//   pre-swizzled DMA source; Q slot sd^(td>>3).
//   Epilogue: kl-butterfly(1,2,4); kl==0 lanes store P[ks][b][chunk][64][32].
// k1c: 256 blocks: sum 16 K-slices -> argmax -> buckets + 64-chunk hist.
// k2/k3: 64-token-chunk scan + stable scatter (verified round 1, verbatim).

#define B_DIM 4
#define S_LEN 4096
#define D_DIM 1024
#define NRR 32
#define NBK 64
#define TMK 64                  // tokens per chunk (= hist chunk)
#define NCHUNK (S_LEN / TMK)    // 64
#define NKS 16                  // K slices of 64
#define QOFF 512                // f4 offset of Q region (R slice = 512 f4)
#define PSL 2048                // f32 per partial slice: 64 tok x 32 r

typedef const __attribute__((address_space(1))) void* gas_t;
typedef __attribute__((address_space(3))) void* las_t;

#define FMA4(A, S, B)                                                        \
    (A).x = fmaf((S), (B).x, (A).x); (A).y = fmaf((S), (B).y, (A).y);        \
    (A).z = fmaf((S), (B).z, (A).z); (A).w = fmaf((S), (B).w, (A).w);

__global__ void __launch_bounds__(256) __attribute__((amdgpu_waves_per_eu(4, 4)))
k1_gemm(const float* __restrict__ Q, const float* __restrict__ R,
        float4* __restrict__ P4)
{
    __shared__ float4 smem4[QOFF + 1024];   // R slice 8KB + 4 waves x 256 f4 Q

    const int bid = blockIdx.x;
    const int ks = bid & 15;
    const int chunk = (bid >> 4) & 63;
    const int b = bid >> 10;

    const int t = threadIdx.x;
    const int w = t >> 6;
    const int lane = t & 63;
    const int tok_t = lane >> 5;         // 2 groups x 8 tokens
    const int r_t = (lane >> 3) & 3;     // 4 groups x 8 r (2 f4)
    const int kl = lane & 7;             // 8-way k split (8 k = 2 f4 each)
    const int rsw0 = (r_t * 2 + 0) ^ kl;
    const int rsw1 = (r_t * 2 + 1) ^ kl;

    const float4* Qw4 = (const float4*)(Q + ((size_t)b * S_LEN + chunk * TMK + w * 16) * D_DIM);
    const float4* Rg4 = (const float4*)(R + (size_t)b * D_DIM * NRR);

    // ---- prologue: stage R slice (shared) + this wave's Q; one barrier ----
#pragma unroll
    for (int i = 0; i < 2; ++i) {
        const int rel = w * 128 + i * 64 + lane;     // f4 slot in R slice
        const int kh = rel >> 3, v = rel & 7;
        __builtin_amdgcn_global_load_lds(
            (gas_t)(Rg4 + ((size_t)ks * 64 + kh) * 8 + (v ^ ((kh >> 3) & 7))),
            (las_t)&smem4[w * 128 + i * 64], 16, 0, 0);
    }
#pragma unroll
    for (int i = 0; i < 4; ++i) {
        const int f = i * 64 + lane;                 // f4 slot in wave's Q buf
        const int td = f >> 4, sd = f & 15;
        __builtin_amdgcn_global_load_lds(
            (gas_t)(Qw4 + (size_t)td * 256 + ks * 16 + (sd ^ (td >> 3))),
            (las_t)&smem4[QOFF + w * 256 + i * 64], 16, 0, 0);
    }
    asm volatile("s_waitcnt vmcnt(0)" ::: "memory");
    __syncthreads();

    // ---- straight-line compute: 2 passes (kap), R11-verified shape ----
    float4 acc[8][2];
#pragma unroll
    for (int j = 0; j < 8; ++j) {
        acc[j][0] = make_float4(0.f, 0.f, 0.f, 0.f);
        acc[j][1] = make_float4(0.f, 0.f, 0.f, 0.f);
    }
    const float4* rb = smem4;
    const float4* qb = smem4 + QOFF + w * 256;

#pragma unroll
    for (int kap = 0; kap < 2; ++kap) {
        float4 rv[4][2];
#pragma unroll
        for (int c = 0; c < 4; ++c) {
            const int krow = kl * 8 + kap * 4 + c;
            rv[c][0] = rb[krow * 8 + rsw0];
            rv[c][1] = rb[krow * 8 + rsw1];
        }
#pragma unroll
        for (int j = 0; j < 8; ++j) {
            const float4 qv = qb[(tok_t * 8 + j) * 16 + ((kl * 2 + kap) ^ tok_t)];
#pragma unroll
            for (int c = 0; c < 4; ++c) {
                const float s = c == 0 ? qv.x : c == 1 ? qv.y
                              : c == 2 ? qv.z : qv.w;
                FMA4(acc[j][0], s, rv[c][0]);
                FMA4(acc[j][1], s, rv[c][1]);
            }
        }
    }

    // ---- butterfly reduce over kl (lane bits 0-2) ----
#pragma unroll
    for (int j = 0; j < 8; ++j)
#pragma unroll
        for (int p = 0; p < 2; ++p)
#pragma unroll
            for (int off = 1; off < 8; off <<= 1) {
                acc[j][p].x += __shfl_xor(acc[j][p].x, off, 64);
                acc[j][p].y += __shfl_xor(acc[j][p].y, off, 64);
                acc[j][p].z += __shfl_xor(acc[j][p].z, off, 64);
                acc[j][p].w += __shfl_xor(acc[j][p].w, off, 64);
            }

    // ---- kl==0 lanes store the slice partial ----
    if (kl == 0) {
        float4* Pb = P4 + (((size_t)ks * B_DIM + b) * NCHUNK + chunk) * (PSL / 4);
#pragma unroll
        for (int j = 0; j < 8; ++j) {
            const int tok = w * 16 + tok_t * 8 + j;
            Pb[tok * 8 + r_t * 2 + 0] = acc[j][0];
            Pb[tok * 8 + r_t * 2 + 1] = acc[j][1];
        }
    }
}

// 256 blocks = (b, 64-token chunk): sum 16 K-slices, argmax, bucket, hist.
__global__ __launch_bounds__(256) void k1c_combine(
    const float* __restrict__ P,
    int* __restrict__ buckets, int* __restrict__ hist)
{
    __shared__ float xs[TMK][NRR + 1];
    __shared__ int cnt[NBK];

    const int bid = blockIdx.x;
    const int b = bid >> 6;
    const int h = bid & 63;
    const int t = threadIdx.x;

#pragma unroll
    for (int i = 0; i < 8; ++i) {
        const int idx = t + 256 * i;          // 0..2047 = 64 tok x 32 r
        const int tok = idx >> 5, r = idx & 31;
        float s = 0.f;
#pragma unroll
        for (int ks = 0; ks < NKS; ++ks)
            s += P[(((size_t)ks * B_DIM + b) * NCHUNK + h) * PSL + tok * NRR + r];
        xs[tok][r] = s;
    }
    if (t < NBK) cnt[t] = 0;
    __syncthreads();

    if (t < TMK) {
        // argmax(concat[xR,-xR]) with first-occurrence tie-break
        float m1 = xs[t][0]; int i1 = 0;
        float m2 = m1;       int i2 = 0;
#pragma unroll
        for (int r = 1; r < NRR; ++r) {
            const float v = xs[t][r];
            if (v > m1) { m1 = v; i1 = r; }
            if (v < m2) { m2 = v; i2 = r; }
        }
        const int bk = (m1 >= -m2) ? i1 : (NRR + i2);
        buckets[(size_t)b * S_LEN + h * TMK + t] = bk;
        atomicAdd(&cnt[bk], 1);
    }
    __syncthreads();
    if (t < NBK) hist[((size_t)b * NCHUNK + h) * NBK + t] = cnt[t];
}

// One block, 256 threads: thread = (batch b = t/64, bucket bk = t%64).
__global__ __launch_bounds__(256) void k2_scan(
    const int* __restrict__ hist, int* __restrict__ chunkOffset)
{
    const int t = threadIdx.x;
    const int b = t >> 6;
    const int bk = t & 63;
    const int lane = t & 63;

    int total = 0;
    for (int c = 0; c < NCHUNK; ++c)
        total += hist[((size_t)b * NCHUNK + c) * NBK + bk];

    int incl = total;
#pragma unroll
    for (int off = 1; off < 64; off <<= 1) {
        int n = __shfl_up(incl, off, 64);
        if (lane >= off) incl += n;
    }
    int run = incl - total;   // exclusive prefix over buckets = bucketStart

    for (int c = 0; c < NCHUNK; ++c) {
        int h = hist[((size_t)b * NCHUNK + c) * NBK + bk];
        chunkOffset[((size_t)b * NCHUNK + c) * NBK + bk] = run;
        run += h;
    }
}

// Stable scatter: wave = 64 consecutive tokens (one chunk).
__global__ __launch_bounds__(256) void k3_scatter(
    const int* __restrict__ buckets, const int* __restrict__ chunkOffset,
    int* __restrict__ out)
{
    const int gid = blockIdx.x * 256 + threadIdx.x;  // 0..16383
    const int b = gid >> 12;
    const int s = gid & (S_LEN - 1);
    const int chunk = s >> 6;
    const int lane = threadIdx.x & 63;

    const int bk = buckets[gid];

    unsigned long long m = ~0ull;
#pragma unroll
    for (int i = 0; i < 6; ++i) {
        unsigned long long bi = __ballot((bk >> i) & 1);
        m &= ((bk >> i) & 1) ? bi : ~bi;
    }
    int rank = __popcll(m & ((1ull << lane) - 1ull));

    int pos = chunkOffset[((size_t)b * NCHUNK + chunk) * NBK + bk] + rank;
    out[(size_t)b * S_LEN + pos] = s;
}

extern "C" void kernel_launch(void* const* d_in, const int* in_sizes, int n_in,
                              void* d_out, int out_size, void* d_ws, size_t ws_size,
                              hipStream_t stream) {
    const float* Q = (const float*)d_in[0];
    // d_in[1] = key, d_in[2] = value: dead code in the reference, never read.
    const float* R = (const float*)d_in[3];

    float* P         = (float*)d_ws;   // 16*4*64*2048 f32 = 32 MB partials
    int* buckets     = (int*)(P + (size_t)NKS * B_DIM * NCHUNK * PSL);
    int* hist        = buckets + B_DIM * S_LEN;
    int* chunkOffset = hist + B_DIM * NCHUNK * NBK;

    k1_gemm    <<<B_DIM * NCHUNK * NKS, 256, 0, stream>>>(Q, R, (float4*)P);
    k1c_combine<<<B_DIM * NCHUNK,       256, 0, stream>>>(P, buckets, hist);
    k2_scan    <<<1,                    256, 0, stream>>>(hist, chunkOffset);
    k3_scatter <<<(B_DIM * S_LEN) / 256, 256, 0, stream>>>(buckets, chunkOffset, (int*)d_out);
}

// Round 19
// 43.501 us; speedup vs baseline: 1.6303x; 1.6303x over previous
//
#include <hip/hip_runtime.h>

// LSHAttention: reference returns ONLY sticker = argsort(buckets) [B,S] int32.
// B=4, S=4096, D=1024, NR=32, 64 buckets.
//
// ROUND 19 = ROUND 17 (best k1: 38.4us) with ALL global_load_lds DMA replaced
// by plain coalesced ascending global loads -> regs -> ds_write (swizzle moved
// to the LDS-WRITE address; global side linear). Rationale: every DMA-based
// kernel (R7-R17) capped at ~850 GB/s staged traffic, while our spill kernels'
// register-path vmem sustained 2.5-3.8 TB/s on the same chip -- the DMA path
// (with permuted source) is the hidden binder. T14: qs loads issued BEFORE
// COMPUTE, ds_write after (compiler sinks the vmcnt to first use).
//
// k1: grid 1024 = (b:4, chunk:64 -> 64 tok, kqr:4 -> 256 k), 256 thr = 4 waves.
//   Wave w owns tokens [w*16,w*16+16). LDS 64KB = R quarter 32KB (read-only,
//   staged once) + 4x wave-private Q dbuf -> 2 blocks/CU. ONE barrier total.
//   Lane = (tok_t:2 x8tok, r_t:4 x8r, kl:8); acc = 8tok x 8r = 64 f32.
//   LDS layouts (IDENTICAL to R17's, now via write-side swizzle):
//     R slot = kh*8 + (v ^ ((kh>>3)&7)); Q slot = td*16 + (sd ^ (td>>3)).
//   Epilogue: kl-butterfly; kl==0 lanes store P[b][chunk][kqr][64][32].
// k1c: sum 4 quarters -> argmax -> buckets + 64-chunk hist (R17 verbatim).
// k2/k3: 64-token-chunk scan + stable scatter (verified round 1, verbatim).

#define B_DIM 4
#define S_LEN 4096
#define D_DIM 1024
#define NRR 32
#define NBK 64
#define TMK 64                  // tokens per chunk (= hist chunk)
#define NCHUNK (S_LEN / TMK)    // 64
#define NKQ 4                   // K quarters
#define QOFF 2048               // f4 offset of Q buffers (R quarter first)
#define PSL 2048                // f32 per partial slice: 64 tok x 32 r

#define FMA4(A, S, B)                                                        \
    (A).x = fmaf((S), (B).x, (A).x); (A).y = fmaf((S), (B).y, (A).y);        \
    (A).z = fmaf((S), (B).z, (A).z); (A).w = fmaf((S), (B).w, (A).w);

__global__ void __launch_bounds__(256) __attribute__((amdgpu_waves_per_eu(2, 2)))
k1_gemm(const float* __restrict__ Q, const float* __restrict__ R,
        float4* __restrict__ P4)
{
    __shared__ float4 smem4[QOFF + 2048];   // R qtr 32KB + 4w x 2buf x 256 f4

    const int bid = blockIdx.x;
    const int kqr = bid & 3;
    const int chunk = (bid >> 2) & 63;
    const int b = bid >> 8;

    const int t = threadIdx.x;
    const int w = t >> 6;
    const int lane = t & 63;
    const int tok_t = lane >> 5;         // 2 groups x 8 tokens
    const int r_t = (lane >> 3) & 3;     // 4 groups x 8 r (2 f4)
    const int kl = lane & 7;             // 8-way k split

    const float4* Qw4 = (const float4*)(Q + ((size_t)b * S_LEN + chunk * TMK + w * 16) * D_DIM);
    const float4* Rg4 = (const float4*)(R + (size_t)b * D_DIM * NRR);

    // ---- Q stage helpers: ascending coalesced loads; swizzled ds_write ----
#define QLOAD(TILE, QS)                                                       \
    {                                                                         \
        _Pragma("unroll")                                                     \
        for (int i = 0; i < 4; ++i) {                                         \
            const int f = i * 64 + lane;                                      \
            const int td = f >> 4, sd = f & 15;                               \
            (QS)[i] = Qw4[(size_t)td * 256 + kqr * 64 + (TILE) * 16 + sd];    \
        }                                                                     \
    }
#define QWRITE(QS, DST)                                                       \
    {                                                                         \
        float4* qb = smem4 + QOFF + w * 512 + (DST) * 256;                    \
        _Pragma("unroll")                                                     \
        for (int i = 0; i < 4; ++i) {                                         \
            const int f = i * 64 + lane;                                      \
            const int td = f >> 4, sd = f & 15;                               \
            qb[td * 16 + (sd ^ (td >> 3))] = (QS)[i];                         \
        }                                                                     \
    }

#define COMPUTE(TILE, BUF)                                                    \
    {                                                                         \
        const float4* qb = smem4 + QOFF + w * 512 + (BUF) * 256;              \
        const float4* rb = smem4;                                             \
        _Pragma("unroll")                                                     \
        for (int kap = 0; kap < 2; ++kap) {                                   \
            float4 qv[8];                                                     \
            _Pragma("unroll")                                                 \
            for (int j = 0; j < 8; ++j)                                       \
                qv[j] = qb[(tok_t * 8 + j) * 16 + (((kl << 1) + kap) ^ tok_t)];\
            _Pragma("unroll")                                                 \
            for (int c = 0; c < 4; ++c) {                                     \
                const int krow = (TILE) * 64 + kl * 8 + kap * 4 + c;          \
                const float4 rv0 = rb[krow * 8 + ((r_t * 2 + 0) ^ kl)];       \
                const float4 rv1 = rb[krow * 8 + ((r_t * 2 + 1) ^ kl)];       \
                _Pragma("unroll")                                             \
                for (int j = 0; j < 8; ++j) {                                 \
                    const float s = c == 0 ? qv[j].x : c == 1 ? qv[j].y       \
                                  : c == 2 ? qv[j].z : qv[j].w;               \
                    FMA4(acc[j][0], s, rv0);                                  \
                    FMA4(acc[j][1], s, rv1);                                  \
                }                                                             \
            }                                                                 \
        }                                                                     \
    }

    float4 acc[8][2];
#pragma unroll
    for (int j = 0; j < 8; ++j) {
        acc[j][0] = make_float4(0.f, 0.f, 0.f, 0.f);
        acc[j][1] = make_float4(0.f, 0.f, 0.f, 0.f);
    }

    // ---- prologue: R quarter + Q tile 0, all via registers; ONE barrier ----
    {
        float4 rs[8];
#pragma unroll
        for (int i = 0; i < 8; ++i)
            rs[i] = Rg4[(size_t)kqr * 2048 + t + 256 * i];   // ascending, coalesced
        float4 qs[4];
        QLOAD(0, qs)
#pragma unroll
        for (int i = 0; i < 8; ++i) {
            const int f = t + 256 * i;
            const int kh = f >> 3, v = f & 7;
            smem4[kh * 8 + (v ^ ((kh >> 3) & 7))] = rs[i];
        }
        QWRITE(qs, 0)
    }
    __syncthreads();

    // ---- main loop: wave-private pacing, no barriers ----
#pragma unroll
    for (int tau = 0; tau < 4; ++tau) {
        float4 qs[4];
        if (tau + 1 < 4) QLOAD(tau + 1, qs)        // issue early (T14)
        COMPUTE(tau, tau & 1)
        if (tau + 1 < 4) QWRITE(qs, (tau + 1) & 1) // write-late; compiler fences
    }
#undef QLOAD
#undef QWRITE
#undef COMPUTE

    // ---- butterfly reduce over kl (lane bits 0-2) ----
#pragma unroll
    for (int j = 0; j < 8; ++j)
#pragma unroll
        for (int p = 0; p < 2; ++p)
#pragma unroll
            for (int off = 1; off < 8; off <<= 1) {
                acc[j][p].x += __shfl_xor(acc[j][p].x, off, 64);
                acc[j][p].y += __shfl_xor(acc[j][p].y, off, 64);
                acc[j][p].z += __shfl_xor(acc[j][p].z, off, 64);
                acc[j][p].w += __shfl_xor(acc[j][p].w, off, 64);
            }

    // ---- kl==0 lanes hold full quarter-sums: store partial slice ----
    if (kl == 0) {
        float4* Pb = P4 + (((size_t)b * NCHUNK + chunk) * NKQ + kqr) * (PSL / 4);
#pragma unroll
        for (int j = 0; j < 8; ++j) {
            const int tok = w * 16 + tok_t * 8 + j;
            Pb[tok * 8 + r_t * 2 + 0] = acc[j][0];
            Pb[tok * 8 + r_t * 2 + 1] = acc[j][1];
        }
    }
}

// 256 blocks = (b, 64-token chunk): sum 4 K-quarters, argmax, bucket, hist.
__global__ __launch_bounds__(256) void k1c_combine(
    const float* __restrict__ P,
    int* __restrict__ buckets, int* __restrict__ hist)
{
    __shared__ float xs[TMK][NRR + 1];
    __shared__ int cnt[NBK];

    const int bid = blockIdx.x;
    const int b = bid >> 6;
    const int h = bid & 63;
    const int t = threadIdx.x;

    const float* Pb = P + ((size_t)b * NCHUNK + h) * NKQ * PSL;
#pragma unroll
    for (int i = 0; i < 8; ++i) {
        const int idx = t + 256 * i;          // 0..2047 = 64 tok x 32 r
        const int tok = idx >> 5, r = idx & 31;
        const size_t base = (size_t)tok * NRR + r;
        xs[tok][r] = Pb[base] + Pb[base + PSL] + Pb[base + 2 * PSL] + Pb[base + 3 * PSL];
    }
    if (t < NBK) cnt[t] = 0;
    __syncthreads();

    if (t < TMK) {
        // argmax(concat[xR,-xR]) with first-occurrence tie-break
        float m1 = xs[t][0]; int i1 = 0;
        float m2 = m1;       int i2 = 0;
#pragma unroll
        for (int r = 1; r < NRR; ++r) {
            const float v = xs[t][r];
            if (v > m1) { m1 = v; i1 = r; }
            if (v < m2) { m2 = v; i2 = r; }
        }
        const int bk = (m1 >= -m2) ? i1 : (NRR + i2);
        buckets[(size_t)b * S_LEN + h * TMK + t] = bk;
        atomicAdd(&cnt[bk], 1);
    }
    __syncthreads();
    if (t < NBK) hist[((size_t)b * NCHUNK + h) * NBK + t] = cnt[t];
}

// One block, 256 threads: thread = (batch b = t/64, bucket bk = t%64).
__global__ __launch_bounds__(256) void k2_scan(
    const int* __restrict__ hist, int* __restrict__ chunkOffset)
{
    const int t = threadIdx.x;
    const int b = t >> 6;
    const int bk = t & 63;
    const int lane = t & 63;

    int total = 0;
    for (int c = 0; c < NCHUNK; ++c)
        total += hist[((size_t)b * NCHUNK + c) * NBK + bk];

    int incl = total;
#pragma unroll
    for (int off = 1; off < 64; off <<= 1) {
        int n = __shfl_up(incl, off, 64);
        if (lane >= off) incl += n;
    }
    int run = incl - total;   // exclusive prefix over buckets = bucketStart

    for (int c = 0; c < NCHUNK; ++c) {
        int h = hist[((size_t)b * NCHUNK + c) * NBK + bk];
        chunkOffset[((size_t)b * NCHUNK + c) * NBK + bk] = run;
        run += h;
    }
}

// Stable scatter: wave = 64 consecutive tokens (one chunk).
__global__ __launch_bounds__(256) void k3_scatter(
    const int* __restrict__ buckets, const int* __restrict__ chunkOffset,
    int* __restrict__ out)
{
    const int gid = blockIdx.x * 256 + threadIdx.x;  // 0..16383
    const int b = gid >> 12;
    const int s = gid & (S_LEN - 1);
    const int chunk = s >> 6;
    const int lane = threadIdx.x & 63;

    const int bk = buckets[gid];

    unsigned long long m = ~0ull;
#pragma unroll
    for (int i = 0; i < 6; ++i) {
        unsigned long long bi = __ballot((bk >> i) & 1);
        m &= ((bk >> i) & 1) ? bi : ~bi;
    }
    int rank = __popcll(m & ((1ull << lane) - 1ull));

    int pos = chunkOffset[((size_t)b * NCHUNK + chunk) * NBK + bk] + rank;
    out[(size_t)b * S_LEN + pos] = s;
}

extern "C" void kernel_launch(void* const* d_in, const int* in_sizes, int n_in,
                              void* d_out, int out_size, void* d_ws, size_t ws_size,
                              hipStream_t stream) {
    const float* Q = (const float*)d_in[0];
    // d_in[1] = key, d_in[2] = value: dead code in the reference, never read.
    const float* R = (const float*)d_in[3];

    float* P         = (float*)d_ws;   // 4*64*4*2048 f32 = 8 MB partials
    int* buckets     = (int*)(P + (size_t)B_DIM * NCHUNK * NKQ * PSL);
    int* hist        = buckets + B_DIM * S_LEN;
    int* chunkOffset = hist + B_DIM * NCHUNK * NBK;

    k1_gemm    <<<B_DIM * NCHUNK * NKQ, 256, 0, stream>>>(Q, R, (float4*)P);
    k1c_combine<<<B_DIM * NCHUNK,       256, 0, stream>>>(P, buckets, hist);
    k2_scan    <<<1,                    256, 0, stream>>>(hist, chunkOffset);
    k3_scatter <<<(B_DIM * S_LEN) / 256, 256, 0, stream>>>(buckets, chunkOffset, (int*)d_out);
}